// Round 5
// baseline (1981.492 us; speedup 1.0000x reference)
//
#include <hip/hip_runtime.h>
#include <stdint.h>

#define TT 400
#define BB 256
#define II 256
#define HH 512
#define NG 2048  // 4*H

typedef __attribute__((ext_vector_type(8))) _Float16 half8;
typedef __attribute__((ext_vector_type(4))) float f32x4;
typedef __attribute__((ext_vector_type(4))) unsigned int u32x4;
typedef __attribute__((ext_vector_type(2))) unsigned int u32x2;
typedef unsigned int u32;
typedef unsigned short u16;

static __device__ __forceinline__ u32 f2hbits(float f){
  union { _Float16 h; u16 u; } c; c.h = (_Float16)f; return (u32)c.u;
}

#define GLOAD16(gsrc, ldst) \
  __builtin_amdgcn_global_load_lds((const __attribute__((address_space(1))) void*)(gsrc), \
                                   (__attribute__((address_space(3))) void*)(ldst), 16, 0, 0)

// ---------------------------------------------------------------------------
// Transpose x[B][I][T] fp32 -> xT[t][b][i] fp16. Tile 32(i) x 16(t).
__global__ __launch_bounds__(256) void k_prep_x(const float* __restrict__ x,
                                                u16* __restrict__ xT){
  __shared__ float tile[32][17];
  const int bid = blockIdx.x;
  const int tb = bid % 25, ib = (bid / 25) & 7, b = bid / 200;
  const int t0 = tb * 16, i0 = ib * 32;
  const int tl = threadIdx.x & 15, il = threadIdx.x >> 4;
  tile[il][tl]      = x[(size_t)(b * II + i0 + il) * TT + t0 + tl];
  tile[il + 16][tl] = x[(size_t)(b * II + i0 + il + 16) * TT + t0 + tl];
  __syncthreads();
  const int t_l = threadIdx.x >> 4, ip = threadIdx.x & 15;
  const u32 pack = f2hbits(tile[2 * ip][t_l]) | (f2hbits(tile[2 * ip + 1][t_l]) << 16);
  *(u32*)(xT + ((size_t)(t0 + t_l) * BB + b) * II + i0 + 2 * ip) = pack;
}

// ---------------------------------------------------------------------------
// w_ih[2048][256] fp32 -> fp16.
__global__ __launch_bounds__(256) void k_prep_w(const float* __restrict__ w_ih,
                                                u16* __restrict__ Wp){
  const size_t idx = (size_t)blockIdx.x * 256 + threadIdx.x;  // 0..131071
  const float4 v = *(const float4*)(w_ih + idx * 4);
  uint2 o;
  o.x = f2hbits(v.x) | (f2hbits(v.y) << 16);
  o.y = f2hbits(v.z) | (f2hbits(v.w) << 16);
  *(uint2*)(Wp + idx * 4) = o;
}

// ---------------------------------------------------------------------------
// xg[M=102400][2048] fp16 = A[M][256] @ Wp[2048][256]^T, fp16 MFMA, K=256.
__global__ __launch_bounds__(256) void k_gemm_xg(const u16* __restrict__ A,
                                                 const u16* __restrict__ B,
                                                 _Float16* __restrict__ xg){
  __shared__ char lds[65536];  // A: buf*16384 ; B: 32768 + buf*16384
  const int tid = threadIdx.x, w = tid >> 6, lane = tid & 63;
  const int nb = blockIdx.x & 15, mb = blockIdx.x >> 4;
  const size_t m0 = (size_t)mb * 128;
  const int n0 = nb * 128;
  const int lr = lane & 15, lh = lane >> 4;

  auto stage = [&](int it, int buf){
    const size_t kb = (size_t)it * 128;  // 64 fp16 per k-step
    #pragma unroll
    for (int i2 = 0; i2 < 4; ++i2){
      const int u = w * 256 + i2 * 64 + lane;
      const int r = u >> 3, s = u & 7;
      const char* g = (const char*)A + (m0 + r) * 512 + kb + ((s ^ (r & 7)) << 4);
      char* l = lds + buf * 16384 + ((w * 256 + i2 * 64) << 4);
      GLOAD16(g, l);
    }
    #pragma unroll
    for (int i2 = 0; i2 < 4; ++i2){
      const int u = w * 256 + i2 * 64 + lane;
      const int r = u >> 3, s = u & 7;
      const char* g = (const char*)B + (size_t)(n0 + r) * 512 + kb + ((s ^ (r & 7)) << 4);
      char* l = lds + 32768 + buf * 16384 + ((w * 256 + i2 * 64) << 4);
      GLOAD16(g, l);
    }
  };

  f32x4 acc[4][4];
  #pragma unroll
  for (int i = 0; i < 4; ++i)
    #pragma unroll
    for (int j = 0; j < 4; ++j){ f32x4 z = {0.f,0.f,0.f,0.f}; acc[i][j] = z; }

  const int wm = (w & 1) * 64, wn = (w >> 1) * 64;
  stage(0, 0);
  for (int it = 0; it < 4; ++it){
    const int buf = it & 1;
    if (it < 3) stage(it + 1, buf ^ 1);
    __syncthreads();
    const char* lA = lds + buf * 16384;
    const char* lB = lds + 32768 + buf * 16384;
    #pragma unroll
    for (int ks = 0; ks < 2; ++ks){
      half8 a[4], b[4];
      const int s = ks * 4 + lh;
      #pragma unroll
      for (int mt = 0; mt < 4; ++mt){
        const int r = wm + mt * 16 + lr;
        a[mt] = *(const half8*)(lA + r * 128 + ((s ^ (r & 7)) << 4));
      }
      #pragma unroll
      for (int nt = 0; nt < 4; ++nt){
        const int r = wn + nt * 16 + lr;
        b[nt] = *(const half8*)(lB + r * 128 + ((s ^ (r & 7)) << 4));
      }
      #pragma unroll
      for (int mt = 0; mt < 4; ++mt)
        #pragma unroll
        for (int nt = 0; nt < 4; ++nt)
          acc[mt][nt] = __builtin_amdgcn_mfma_f32_16x16x32_f16(a[mt], b[nt], acc[mt][nt], 0, 0, 0);
    }
    __syncthreads();
  }
  #pragma unroll
  for (int mt = 0; mt < 4; ++mt)
    #pragma unroll
    for (int nt = 0; nt < 4; ++nt)
      #pragma unroll
      for (int r = 0; r < 4; ++r){
        const size_t row = m0 + wm + mt * 16 + lh * 4 + r;
        const int col = n0 + wn + nt * 16 + lr;
        xg[row * NG + col] = (_Float16)acc[mt][nt][r];
      }
}

// ---------------------------------------------------------------------------
// Persistent recurrent kernel, A/B phase-interleaved with speculative polls.
// 8 megagroups x 32 batch rows; 16 col-WGs each (32 h-cols). Grid = 128 WGs.
// Subgroup A = rows [b0,b0+16), B = [b0+16,b0+32) — same W slice, alternate
// phases; each phase's h-store latency hides under the other phase's compute.
// htag[2][256][512] u32: low16 = fp16(h), high16 = step tag (t+1).
__global__ __launch_bounds__(512) void k_lstm(const _Float16* __restrict__ xg,
    const float* __restrict__ w_hh, const float* __restrict__ b_ih,
    const float* __restrict__ b_hh, u32* __restrict__ htag,
    float* __restrict__ out){
  extern __shared__ char lds[];
  char* Wl  = lds;                        // 131072 B: [128 gate rows][512 fp16]
  char* hbA = lds + 131072;               //  16384 B: A-stage [16][512] fp16 swz
  char* hbB = lds + 147456;               //  16384 B: B-stage
  float* gbufA = (float*)(lds + 147456);  // alias hbB (barrier-separated)
  float* gbufB = (float*)(lds + 131072);  // alias hbA (barrier-separated)

  const int tid = threadIdx.x, w = tid >> 6, lane = tid & 63;
  const int lr = lane & 15, lh = lane >> 4;
  const int mg = blockIdx.x >> 4, gn = blockIdx.x & 15;
  const int b0 = mg * 32, j0 = gn * 32;

  // ---- w_hh slice fp32 -> fp16 -> LDS (once), XOR-swizzled 16B units
  for (int rep = 0; rep < 16; ++rep){
    const int u = rep * 512 + tid;        // 0..8191 units
    const int row = u >> 6, u0 = u & 63;
    const int grow = ((row >> 5) << 9) + j0 + (row & 31);
    const float* src = w_hh + (size_t)grow * HH + u0 * 8;
    const float4 va = *(const float4*)src;
    const float4 vb = *(const float4*)(src + 4);
    union { _Float16 h[8]; u32x4 v; } p;
    p.h[0] = (_Float16)va.x; p.h[1] = (_Float16)va.y;
    p.h[2] = (_Float16)va.z; p.h[3] = (_Float16)va.w;
    p.h[4] = (_Float16)vb.x; p.h[5] = (_Float16)vb.y;
    p.h[6] = (_Float16)vb.z; p.h[7] = (_Float16)vb.w;
    *(u32x4*)(Wl + row * 1024 + ((u0 ^ (row & 7)) << 4)) = p.v;
  }
  const int brow = tid >> 5, jj = tid & 31;
  float biasv[4];
  #pragma unroll
  for (int q2 = 0; q2 < 4; ++q2)
    biasv[q2] = b_ih[q2 * HH + j0 + jj] + b_hh[q2 * HH + j0 + jj];
  float cA = 0.f, cB = 0.f;
  const int q = w >> 1, jb = w & 1;
  const int nrow = q * 32 + jb * 16 + lr;
  const int nbase = nrow * 1024, nx = nrow & 7, ax = lr & 7;

  // stage addressing: 2048 16B-units = [16 rows][128 units of 4 tagged cols]
  size_t sgof[4]; int slof[4];
  #pragma unroll
  for (int k = 0; k < 4; ++k){
    const int u = k * 512 + tid;
    const int row = u >> 7, cu = u & 127;
    sgof[k] = (size_t)row * 512 + cu * 4;                       // u32 index
    slof[k] = row * 1024 + ((((cu >> 1) ^ (row & 7)) << 4) | ((cu & 1) << 3));
  }

#define SPEC_ISSUE(S0,S1,S2,S3, P) \
  asm volatile("global_load_dwordx4 %0, %4, off sc0 sc1\n\t" \
               "global_load_dwordx4 %1, %5, off sc0 sc1\n\t" \
               "global_load_dwordx4 %2, %6, off sc0 sc1\n\t" \
               "global_load_dwordx4 %3, %7, off sc0 sc1" \
               : "=&v"(S0), "=&v"(S1), "=&v"(S2), "=&v"(S3) \
               : "v"((P) + sgof[0]), "v"((P) + sgof[1]), \
                 "v"((P) + sgof[2]), "v"((P) + sgof[3]) : "memory")

#define XG_ISSUE(X0,X1,X2,X3, PT) \
  asm volatile("global_load_ushort %0, %4, off\n\t" \
               "global_load_ushort %1, %5, off\n\t" \
               "global_load_ushort %2, %6, off\n\t" \
               "global_load_ushort %3, %7, off" \
               : "=&v"(X0), "=&v"(X1), "=&v"(X2), "=&v"(X3) \
               : "v"(PT), "v"((PT) + HH), "v"((PT) + 2 * HH), "v"((PT) + 3 * HH) \
               : "memory")

#define SPEC_CONSUME(S0,S1,S2,S3, P, TE, HB) do { \
  asm volatile("" : "+v"(S0), "+v"(S1), "+v"(S2), "+v"(S3)); \
  int need_ = 15, guard_ = 0; \
  while (true){ \
    u32 m_; \
    if (need_ & 1){ m_ = (S0[0]^(TE))|(S0[1]^(TE))|(S0[2]^(TE))|(S0[3]^(TE)); if (!(m_ >> 16)) need_ &= ~1; } \
    if (need_ & 2){ m_ = (S1[0]^(TE))|(S1[1]^(TE))|(S1[2]^(TE))|(S1[3]^(TE)); if (!(m_ >> 16)) need_ &= ~2; } \
    if (need_ & 4){ m_ = (S2[0]^(TE))|(S2[1]^(TE))|(S2[2]^(TE))|(S2[3]^(TE)); if (!(m_ >> 16)) need_ &= ~4; } \
    if (need_ & 8){ m_ = (S3[0]^(TE))|(S3[1]^(TE))|(S3[2]^(TE))|(S3[3]^(TE)); if (!(m_ >> 16)) need_ &= ~8; } \
    if (!need_ || ++guard_ >= (1 << 18)) break; \
    if (need_ & 1) asm volatile("global_load_dwordx4 %0, %1, off sc0 sc1" : "=&v"(S0) : "v"((P) + sgof[0]) : "memory"); \
    if (need_ & 2) asm volatile("global_load_dwordx4 %0, %1, off sc0 sc1" : "=&v"(S1) : "v"((P) + sgof[1]) : "memory"); \
    if (need_ & 4) asm volatile("global_load_dwordx4 %0, %1, off sc0 sc1" : "=&v"(S2) : "v"((P) + sgof[2]) : "memory"); \
    if (need_ & 8) asm volatile("global_load_dwordx4 %0, %1, off sc0 sc1" : "=&v"(S3) : "v"((P) + sgof[3]) : "memory"); \
    asm volatile("s_waitcnt vmcnt(0)" ::: "memory"); \
    __builtin_amdgcn_sched_barrier(0); \
    asm volatile("" : "+v"(S0), "+v"(S1), "+v"(S2), "+v"(S3)); \
  } \
  u32x2 w0_, w1_, w2_, w3_; \
  w0_[0] = (S0[0] & 0xffffu) | (S0[1] << 16); w0_[1] = (S0[2] & 0xffffu) | (S0[3] << 16); \
  w1_[0] = (S1[0] & 0xffffu) | (S1[1] << 16); w1_[1] = (S1[2] & 0xffffu) | (S1[3] << 16); \
  w2_[0] = (S2[0] & 0xffffu) | (S2[1] << 16); w2_[1] = (S2[2] & 0xffffu) | (S2[3] << 16); \
  w3_[0] = (S3[0] & 0xffffu) | (S3[1] << 16); w3_[1] = (S3[2] & 0xffffu) | (S3[3] << 16); \
  *(u32x2*)((HB) + slof[0]) = w0_; *(u32x2*)((HB) + slof[1]) = w1_; \
  *(u32x2*)((HB) + slof[2]) = w2_; *(u32x2*)((HB) + slof[3]) = w3_; \
} while (0)

#define PHASE_ENTRY(T) do { \
  if ((T) == 0) asm volatile("s_waitcnt vmcnt(0)" ::: "memory"); \
  else          asm volatile("s_waitcnt vmcnt(2)" ::: "memory"); \
  __builtin_amdgcn_sched_barrier(0); \
} while (0)

#define GEMM_PHASE(HB, GB) do { \
  f32x4 ac0 = {0.f,0.f,0.f,0.f}, ac1 = {0.f,0.f,0.f,0.f}; \
  const char* abase_ = (HB) + lr * 1024; \
  _Pragma("unroll") \
  for (int ks = 0; ks < 16; ks += 2){ \
    const int s0_ = ks * 4 + lh, s1_ = s0_ + 4; \
    const half8 av0 = *(const half8*)(abase_ + ((s0_ ^ ax) << 4)); \
    const half8 bv0 = *(const half8*)(Wl + nbase + ((s0_ ^ nx) << 4)); \
    ac0 = __builtin_amdgcn_mfma_f32_16x16x32_f16(av0, bv0, ac0, 0, 0, 0); \
    const half8 av1 = *(const half8*)(abase_ + ((s1_ ^ ax) << 4)); \
    const half8 bv1 = *(const half8*)(Wl + nbase + ((s1_ ^ nx) << 4)); \
    ac1 = __builtin_amdgcn_mfma_f32_16x16x32_f16(av1, bv1, ac1, 0, 0, 0); \
  } \
  const f32x4 acs_ = ac0 + ac1; \
  _Pragma("unroll") \
  for (int r = 0; r < 4; ++r) \
    (GB)[(q * 16 + lh * 4 + r) * 32 + jb * 16 + lr] = acs_[r]; \
} while (0)

#define POINTWISE(X0,X1,X2,X3, GB, CREF, ROFF, T) do { \
  asm volatile("" : "+v"(X0), "+v"(X1), "+v"(X2), "+v"(X3)); \
  float g4_[4]; \
  union { u32 u; _Float16 h[2]; } cv_; \
  cv_.u = X0; g4_[0] = (float)cv_.h[0] + biasv[0]; \
  cv_.u = X1; g4_[1] = (float)cv_.h[0] + biasv[1]; \
  cv_.u = X2; g4_[2] = (float)cv_.h[0] + biasv[2]; \
  cv_.u = X3; g4_[3] = (float)cv_.h[0] + biasv[3]; \
  if ((T) > 0){ \
    g4_[0] += (GB)[(0 * 16 + brow) * 32 + jj]; \
    g4_[1] += (GB)[(1 * 16 + brow) * 32 + jj]; \
    g4_[2] += (GB)[(2 * 16 + brow) * 32 + jj]; \
    g4_[3] += (GB)[(3 * 16 + brow) * 32 + jj]; \
  } \
  const float i_ = 1.f / (1.f + __expf(-g4_[0])); \
  const float f_ = 1.f / (1.f + __expf(-g4_[1])); \
  const float ea_ = __expf(-2.f * fabsf(g4_[2])); \
  const float g_ = __builtin_copysignf((1.f - ea_) / (1.f + ea_), g4_[2]); \
  const float o_ = 1.f / (1.f + __expf(-g4_[3])); \
  CREF = f_ * CREF + i_ * g_; \
  const float eb_ = __expf(-2.f * fabsf(CREF)); \
  const float th_ = __builtin_copysignf((1.f - eb_) / (1.f + eb_), CREF); \
  const float hn_ = o_ * th_; \
  if ((T) < TT - 1){ \
    u32* ph_ = htag + (size_t)((T) & 1) * 131072 + (size_t)(b0 + (ROFF) + brow) * 512 + j0 + jj; \
    const u32 hv_ = f2hbits(hn_) | ((u32)((T) + 1) << 16); \
    asm volatile("global_store_dword %0, %1, off sc0 sc1" :: "v"(ph_), "v"(hv_) : "memory"); \
  } \
  out[(size_t)(T) * (BB * HH) + (size_t)(b0 + (ROFF) + brow) * HH + j0 + jj] = CREF; \
} while (0)

  u32x4 sA0, sA1, sA2, sA3, sB0, sB1, sB2, sB3;
  u32 xa0, xa1, xa2, xa3, xb0, xb1, xb2, xb3;

  // preload xg for phase A, t=0
  {
    const _Float16* pt = xg + (size_t)(b0 + brow) * NG + j0 + jj;
    XG_ISSUE(xa0, xa1, xa2, xa3, pt);
  }
  __syncthreads();  // W ready

  for (int t = 0; t < TT; ++t){
    const u32 te = ((u32)t) << 16;
    // ================= PHASE A =================
    PHASE_ENTRY(t);
    if (t > 0){
      u32* pbA = htag + (size_t)((t - 1) & 1) * 131072 + (size_t)b0 * 512;
      SPEC_CONSUME(sA0, sA1, sA2, sA3, pbA, te, hbA);
      __syncthreads();  // B1: stage A ready
      {  // speculative issue for phase B of this step
        u32* pbB = htag + (size_t)((t - 1) & 1) * 131072 + (size_t)(b0 + 16) * 512;
        SPEC_ISSUE(sB0, sB1, sB2, sB3, pbB);
        const _Float16* pt = xg + (size_t)t * (BB * NG) + (size_t)(b0 + 16 + brow) * NG + j0 + jj;
        XG_ISSUE(xb0, xb1, xb2, xb3, pt);
      }
      GEMM_PHASE(hbA, gbufA);
      __syncthreads();  // B2: gbufA ready
    } else {
      const _Float16* pt = xg + (size_t)(b0 + 16 + brow) * NG + j0 + jj;
      XG_ISSUE(xb0, xb1, xb2, xb3, pt);
    }
    POINTWISE(xa0, xa1, xa2, xa3, gbufA, cA, 0, t);
    __syncthreads();    // B3: gbufA reads done before hbB overwrite
    // ================= PHASE B =================
    PHASE_ENTRY(t);
    if (t > 0){
      u32* pbB = htag + (size_t)((t - 1) & 1) * 131072 + (size_t)(b0 + 16) * 512;
      SPEC_CONSUME(sB0, sB1, sB2, sB3, pbB, te, hbB);
      __syncthreads();  // B1': stage B ready
    }
    if (t < TT - 1){    // speculative issue for phase A of step t+1
      u32* pbA = htag + (size_t)(t & 1) * 131072 + (size_t)b0 * 512;
      SPEC_ISSUE(sA0, sA1, sA2, sA3, pbA);
      const _Float16* pt = xg + (size_t)(t + 1) * (BB * NG) + (size_t)(b0 + brow) * NG + j0 + jj;
      XG_ISSUE(xa0, xa1, xa2, xa3, pt);
    }
    if (t > 0){
      GEMM_PHASE(hbB, gbufB);
      __syncthreads();  // B2': gbufB ready
    }
    POINTWISE(xb0, xb1, xb2, xb3, gbufB, cB, 16, t);
    __syncthreads();    // B3': gbufB reads done before hbA overwrite
  }
#undef SPEC_ISSUE
#undef XG_ISSUE
#undef SPEC_CONSUME
#undef PHASE_ENTRY
#undef GEMM_PHASE
#undef POINTWISE
}

// ---------------------------------------------------------------------------
extern "C" void kernel_launch(void* const* d_in, const int* in_sizes, int n_in,
                              void* d_out, int out_size, void* d_ws, size_t ws_size,
                              hipStream_t stream){
  const float* x    = (const float*)d_in[0];
  const float* w_ih = (const float*)d_in[1];
  const float* w_hh = (const float*)d_in[2];
  const float* b_ih = (const float*)d_in[3];
  const float* b_hh = (const float*)d_in[4];
  float* out = (float*)d_out;
  char* ws = (char*)d_ws;

  const size_t o_xg  = 0;             // fp16 [400][256][2048] = 419,430,400 B
  const size_t o_xt  = 419430400;     // fp16 [400][256][256]  =  52,428,800 B
  const size_t o_wp  = 471859200;     // fp16 [2048][256]      =   1,048,576 B
  const size_t o_h   = 472907776;     // u32 [2][256][512]     =   1,048,576 B
  const size_t need  = 473956352;
  if (ws_size < need) return;

  _Float16* xg = (_Float16*)(ws + o_xg);
  u16* xt  = (u16*)(ws + o_xt);
  u16* wp  = (u16*)(ws + o_wp);
  u32* ht  = (u32*)(ws + o_h);

  hipMemsetAsync(ht, 0, 1048576, stream);  // clear stale tags (replay safety)
  hipLaunchKernelGGL(k_prep_x, dim3(51200), dim3(256), 0, stream, x, xt);
  hipLaunchKernelGGL(k_prep_w, dim3(512), dim3(256), 0, stream, w_ih, wp);
  hipLaunchKernelGGL(k_gemm_xg, dim3(12800), dim3(256), 0, stream, xt, wp, xg);
  hipLaunchKernelGGL(k_lstm, dim3(128), dim3(512), 163840, stream,
                     xg, w_hh, b_ih, b_hh, ht, out);
}